// Round 1
// baseline (3263.401 us; speedup 1.0000x reference)
//
#include <hip/hip_runtime.h>
#include <hip/hip_bf16.h>
#include <cstdint>

#define EDGES 400000
#define NODES 50000
#define HDIM  128

typedef unsigned short u16;
typedef __bf16 bf16x8 __attribute__((ext_vector_type(8)));
typedef float  f32x4  __attribute__((ext_vector_type(4)));

__device__ __forceinline__ float bf2f(u16 u) {
    union { uint32_t i; float f; } w; w.i = ((uint32_t)u) << 16; return w.f;
}
__device__ __forceinline__ u16 f2bf(float f) {
    union { float f; uint32_t i; } w; w.f = f;
    uint32_t x = w.i;
    uint32_t r = (x + 0x7fffu + ((x >> 16) & 1u)) >> 16;   // RNE
    return (u16)r;
}

// ---------------------------------------------------------------------------
// Weight convert + transpose: W[k][n] f32  ->  Wt[n][k] bf16
// ---------------------------------------------------------------------------
__global__ void wt_convert(const float* __restrict__ W, u16* __restrict__ Wt,
                           int K, int Nout) {
    int idx = blockIdx.x * 256 + threadIdx.x;
    if (idx < K * Nout) {
        int n = idx / K, k = idx - n * K;
        Wt[idx] = f2bf(W[(size_t)k * Nout + n]);
    }
}

// ---------------------------------------------------------------------------
// S[n][h] = sum_{e: src==n} edge[e][h] + sum_{e: dst==n} edge[e][h]
// ---------------------------------------------------------------------------
__global__ void scatter_S(const float* __restrict__ edge_rep,
                          const int* __restrict__ src, const int* __restrict__ dst,
                          float* __restrict__ S) {
    size_t stride = (size_t)gridDim.x * blockDim.x;
    for (size_t i = (size_t)blockIdx.x * blockDim.x + threadIdx.x;
         i < (size_t)EDGES * HDIM; i += stride) {
        int e = (int)(i >> 7), h = (int)(i & 127);
        float v = edge_rep[i];
        atomicAdd(&S[(size_t)src[e] * HDIM + h], v);
        atomicAdd(&S[(size_t)dst[e] * HDIM + h], v);
    }
}

// X0[e][0:128]   = node[src]+node[dst];  X0[e][128:256] = S[src]+S[dst]   (bf16)
__global__ void build_x0(const float* __restrict__ node_rep, const float* __restrict__ S,
                         const int* __restrict__ src, const int* __restrict__ dst,
                         u16* __restrict__ X0) {
    size_t stride = (size_t)gridDim.x * blockDim.x;
    for (size_t i = (size_t)blockIdx.x * blockDim.x + threadIdx.x;
         i < (size_t)EDGES * HDIM; i += stride) {
        int e = (int)(i >> 7), h = (int)(i & 127);
        size_t so = (size_t)src[e] * HDIM + h, doo = (size_t)dst[e] * HDIM + h;
        X0[(size_t)e * 256 + h]       = f2bf(node_rep[so] + node_rep[doo]);
        X0[(size_t)e * 256 + 128 + h] = f2bf(S[so] + S[doo]);
    }
}

// ---------------------------------------------------------------------------
// GEMM: Out[M,Nout](bf16) = A[M,K](bf16) @ Wt[Nout,K]^T (bf16), f32 accum.
// Epilogue: per-column sum & sumsq atomically accumulated into stats[0:Nout],
// stats[Nout:2*Nout]. 128x128 tile, 4 waves (2x2), 4x4 16x16x32 frags/wave.
// ---------------------------------------------------------------------------
template<int K>
__global__ __launch_bounds__(256) void gemm_bn(
    const u16* __restrict__ A, const u16* __restrict__ Wt,
    u16* __restrict__ Out, float* __restrict__ stats, int M, int Nout)
{
    __shared__ u16 Al[128][72];   // +8 pad: row pitch 144B -> 2-way bank alias (free)
    __shared__ u16 Bl[128][72];
    const int tid  = threadIdx.x;
    const int lane = tid & 63;
    const int w    = tid >> 6;
    const int wrow = w >> 1, wcol = w & 1;
    const int mrow0 = blockIdx.x * 128;
    const int ncol0 = blockIdx.y * 128;
    f32x4 acc[4][4] = {};

    const int srow = tid >> 3;          // 0..31
    const int sc8  = (tid & 7) * 8;     // 0..56

    for (int k0 = 0; k0 < K; k0 += 64) {
        if (k0) __syncthreads();
        #pragma unroll
        for (int p = 0; p < 4; ++p) {
            int row  = srow + p * 32;
            int grow = mrow0 + row;
            uint4 va = make_uint4(0u, 0u, 0u, 0u);
            if (grow < M)
                va = *reinterpret_cast<const uint4*>(&A[(size_t)grow * K + k0 + sc8]);
            *reinterpret_cast<uint4*>(&Al[row][sc8]) = va;
            uint4 vb = *reinterpret_cast<const uint4*>(&Wt[(size_t)(ncol0 + row) * K + k0 + sc8]);
            *reinterpret_cast<uint4*>(&Bl[row][sc8]) = vb;
        }
        __syncthreads();
        #pragma unroll
        for (int kk = 0; kk < 64; kk += 32) {
            const int lr = lane & 15;
            const int kc = kk + (lane >> 4) * 8;
            bf16x8 af[4], bfr[4];
            #pragma unroll
            for (int m = 0; m < 4; ++m)
                af[m] = *reinterpret_cast<const bf16x8*>(&Al[wrow * 64 + m * 16 + lr][kc]);
            #pragma unroll
            for (int n = 0; n < 4; ++n)
                bfr[n] = *reinterpret_cast<const bf16x8*>(&Bl[wcol * 64 + n * 16 + lr][kc]);
            #pragma unroll
            for (int m = 0; m < 4; ++m)
                #pragma unroll
                for (int n = 0; n < 4; ++n)
                    acc[m][n] = __builtin_amdgcn_mfma_f32_16x16x32_bf16(
                        af[m], bfr[n], acc[m][n], 0, 0, 0);
        }
    }

    const int lr = lane & 15, lq = lane >> 4;
    // store C (bf16)  -- verified C/D layout: col=lane&15, row=(lane>>4)*4+i
    #pragma unroll
    for (int m = 0; m < 4; ++m) {
        #pragma unroll
        for (int n = 0; n < 4; ++n) {
            int col = ncol0 + wcol * 64 + n * 16 + lr;
            #pragma unroll
            for (int i = 0; i < 4; ++i) {
                int row = mrow0 + wrow * 64 + m * 16 + lq * 4 + i;
                if (row < M)
                    Out[(size_t)row * Nout + col] = f2bf(acc[m][n][i]);
            }
        }
    }
    // column stats (padded rows are exact zeros -> contribute nothing)
    #pragma unroll
    for (int n = 0; n < 4; ++n) {
        float s = 0.f, q = 0.f;
        #pragma unroll
        for (int m = 0; m < 4; ++m)
            #pragma unroll
            for (int i = 0; i < 4; ++i) { float v = acc[m][n][i]; s += v; q += v * v; }
        s += __shfl_xor(s, 16); s += __shfl_xor(s, 32);
        q += __shfl_xor(q, 16); q += __shfl_xor(q, 32);
        if (lq == 0) {
            int col = ncol0 + wcol * 64 + n * 16 + lr;
            atomicAdd(&stats[col], s);
            atomicAdd(&stats[Nout + col], q);
        }
    }
}

// scsh[j] = g/sqrt(var+eps); scsh[Nout+j] = b - mean*scale
__global__ void bn_finalize(const float* __restrict__ stats, const float* __restrict__ G,
                            const float* __restrict__ Bi, float* __restrict__ scsh,
                            int Nout, float invM) {
    int j = threadIdx.x;
    if (j < Nout) {
        float mean = stats[j] * invM;
        float var  = stats[Nout + j] * invM - mean * mean;
        float sc   = G[j] / sqrtf(var + 1e-5f);
        scsh[j]        = sc;
        scsh[Nout + j] = Bi[j] - mean * sc;
    }
}

// in-place H = relu(H*scale + shift)   (bf16)
__global__ void bn_apply(u16* __restrict__ Hh, const float* __restrict__ scsh,
                         int mask, int Nout, size_t count) {
    size_t stride = (size_t)gridDim.x * blockDim.x;
    for (size_t i = (size_t)blockIdx.x * blockDim.x + threadIdx.x; i < count; i += stride) {
        int c = (int)(i & mask);
        float v = bf2f(Hh[i]);
        Hh[i] = f2bf(fmaxf(v * scsh[c] + scsh[Nout + c], 0.f));
    }
}

// EN = (1+eps1)*edge_rep + relu(H2*s+t)   (bf16 out)
__global__ void edge_new_k(const float* __restrict__ edge_rep, const u16* __restrict__ H2,
                           const float* __restrict__ scsh, const float* __restrict__ eps1,
                           u16* __restrict__ EN) {
    float e1 = 1.0f + eps1[0];
    size_t stride = (size_t)gridDim.x * blockDim.x;
    for (size_t i = (size_t)blockIdx.x * blockDim.x + threadIdx.x;
         i < (size_t)EDGES * HDIM; i += stride) {
        int h = (int)(i & 127);
        float m = fmaxf(bf2f(H2[i]) * scsh[h] + scsh[128 + h], 0.f);
        EN[i] = f2bf(e1 * edge_rep[i] + m);
    }
}

// edge_out (f32) = relu(H4*s+t)
__global__ void edge_out_k(const u16* __restrict__ H4, const float* __restrict__ scsh,
                           float* __restrict__ out) {
    size_t stride = (size_t)gridDim.x * blockDim.x;
    for (size_t i = (size_t)blockIdx.x * blockDim.x + threadIdx.x;
         i < (size_t)EDGES * HDIM; i += stride) {
        int h = (int)(i & 127);
        out[i] = fmaxf(bf2f(H4[i]) * scsh[h] + scsh[128 + h], 0.f);
    }
}

// An[src] += relu(H6*s+t); An[dst] += ...
__global__ void scatter_e2n(const u16* __restrict__ H6, const float* __restrict__ scsh,
                            const int* __restrict__ src, const int* __restrict__ dst,
                            float* __restrict__ An) {
    size_t stride = (size_t)gridDim.x * blockDim.x;
    for (size_t i = (size_t)blockIdx.x * blockDim.x + threadIdx.x;
         i < (size_t)EDGES * HDIM; i += stride) {
        int e = (int)(i >> 7), h = (int)(i & 127);
        float m = fmaxf(bf2f(H6[i]) * scsh[h] + scsh[128 + h], 0.f);
        atomicAdd(&An[(size_t)src[e] * HDIM + h], m);
        atomicAdd(&An[(size_t)dst[e] * HDIM + h], m);
    }
}

// NI = bf16((1+eps2-degree)*node_rep + An)
__global__ void node_in_k(const float* __restrict__ node_rep, const float* __restrict__ An,
                          const float* __restrict__ degree, const float* __restrict__ eps2,
                          u16* __restrict__ NI) {
    float e2 = 1.0f + eps2[0];
    size_t stride = (size_t)gridDim.x * blockDim.x;
    for (size_t i = (size_t)blockIdx.x * blockDim.x + threadIdx.x;
         i < (size_t)NODES * HDIM; i += stride) {
        int n = (int)(i >> 7);
        NI[i] = f2bf((e2 - degree[n]) * node_rep[i] + An[i]);
    }
}

// node_out (f32) = relu(H8*s+t)
__global__ void node_out_k(const u16* __restrict__ H8, const float* __restrict__ scsh,
                           float* __restrict__ out) {
    size_t stride = (size_t)gridDim.x * blockDim.x;
    for (size_t i = (size_t)blockIdx.x * blockDim.x + threadIdx.x;
         i < (size_t)NODES * HDIM; i += stride) {
        int h = (int)(i & 127);
        out[i] = fmaxf(bf2f(H8[i]) * scsh[h] + scsh[128 + h], 0.f);
    }
}

// ---------------------------------------------------------------------------
extern "C" void kernel_launch(void* const* d_in, const int* in_sizes, int n_in,
                              void* d_out, int out_size, void* d_ws, size_t ws_size,
                              hipStream_t stream) {
    const float* node_rep = (const float*)d_in[0];
    const float* edge_rep = (const float*)d_in[1];
    const float* degree   = (const float*)d_in[2];
    const int*   src      = (const int*)d_in[3];
    const int*   dst      = (const int*)d_in[4];
    const float* eps1     = (const float*)d_in[5];
    const float* eps2     = (const float*)d_in[6];
    const float* nW1  = (const float*)d_in[7];
    const float* nG1  = (const float*)d_in[8];
    const float* nB1  = (const float*)d_in[9];
    const float* nW2  = (const float*)d_in[10];
    const float* nG2  = (const float*)d_in[11];
    const float* nB2  = (const float*)d_in[12];
    const float* e0W1 = (const float*)d_in[13];
    const float* e0G1 = (const float*)d_in[14];
    const float* e0B1 = (const float*)d_in[15];
    const float* e0W2 = (const float*)d_in[16];
    const float* e0G2 = (const float*)d_in[17];
    const float* e0B2 = (const float*)d_in[18];
    const float* e1W1 = (const float*)d_in[19];
    const float* e1G1 = (const float*)d_in[20];
    const float* e1B1 = (const float*)d_in[21];
    const float* e1W2 = (const float*)d_in[22];
    const float* e1G2 = (const float*)d_in[23];
    const float* e1B2 = (const float*)d_in[24];
    const float* e2W1 = (const float*)d_in[25];
    const float* e2G1 = (const float*)d_in[26];
    const float* e2B1 = (const float*)d_in[27];
    const float* e2W2 = (const float*)d_in[28];
    const float* e2G2 = (const float*)d_in[29];
    const float* e2B2 = (const float*)d_in[30];

    // ---- workspace layout (all 256B aligned) ----
    size_t off = 0;
    auto alloc = [&](size_t bytes) -> void* {
        void* p = (char*)d_ws + off;
        off += (bytes + 255) & ~(size_t)255;
        return p;
    };
    u16*   BUF_A = (u16*)alloc((size_t)EDGES * 256 * 2);   // X0 -> H3
    u16*   BUF_B = (u16*)alloc((size_t)EDGES * 256 * 2);   // H1 -> H5
    u16*   BUF_C = (u16*)alloc((size_t)EDGES * 128 * 2);   // H2 -> H4 -> H6
    u16*   BUF_D = (u16*)alloc((size_t)EDGES * 128 * 2);   // edge_new
    float* S     = (float*)alloc((size_t)NODES * 128 * 4);
    float* An    = (float*)alloc((size_t)NODES * 128 * 4);
    u16*   NI    = (u16*)alloc((size_t)NODES * 128 * 2);
    u16*   H7    = (u16*)alloc((size_t)NODES * 256 * 2);
    u16*   H8    = (u16*)alloc((size_t)NODES * 128 * 2);
    u16* Wt_e0_1 = (u16*)alloc(256 * 256 * 2);
    u16* Wt_e0_2 = (u16*)alloc(128 * 256 * 2);
    u16* Wt_e1_1 = (u16*)alloc(256 * 128 * 2);
    u16* Wt_e1_2 = (u16*)alloc(128 * 256 * 2);
    u16* Wt_e2_1 = (u16*)alloc(256 * 128 * 2);
    u16* Wt_e2_2 = (u16*)alloc(128 * 256 * 2);
    u16* Wt_n_1  = (u16*)alloc(256 * 128 * 2);
    u16* Wt_n_2  = (u16*)alloc(128 * 256 * 2);
    float* stats = (float*)alloc(8 * 512 * 4);
    float* scsh  = (float*)alloc(8 * 512 * 4);
    if (off > ws_size) return;   // workspace too small; bail safely

    hipMemsetAsync(S,     0, (size_t)NODES * 128 * 4, stream);
    hipMemsetAsync(An,    0, (size_t)NODES * 128 * 4, stream);
    hipMemsetAsync(stats, 0, 8 * 512 * 4, stream);

    const int EB = 8192;               // grid-stride blocks for E*128 loops
    const float invE = 1.0f / (float)EDGES;
    const float invN = 1.0f / (float)NODES;
    const dim3 gE2(3125, 2), gE1(3125, 1), gN2(391, 2), gN1(391, 1);

    // weights -> bf16 transposed
    wt_convert<<<(256 * 256 + 255) / 256, 256, 0, stream>>>(e0W1, Wt_e0_1, 256, 256);
    wt_convert<<<(128 * 256 + 255) / 256, 256, 0, stream>>>(e0W2, Wt_e0_2, 256, 128);
    wt_convert<<<(256 * 128 + 255) / 256, 256, 0, stream>>>(e1W1, Wt_e1_1, 128, 256);
    wt_convert<<<(128 * 256 + 255) / 256, 256, 0, stream>>>(e1W2, Wt_e1_2, 256, 128);
    wt_convert<<<(256 * 128 + 255) / 256, 256, 0, stream>>>(e2W1, Wt_e2_1, 128, 256);
    wt_convert<<<(128 * 256 + 255) / 256, 256, 0, stream>>>(e2W2, Wt_e2_2, 256, 128);
    wt_convert<<<(256 * 128 + 255) / 256, 256, 0, stream>>>(nW1, Wt_n_1, 128, 256);
    wt_convert<<<(128 * 256 + 255) / 256, 256, 0, stream>>>(nW2, Wt_n_2, 256, 128);

    // graph gathers
    scatter_S<<<EB, 256, 0, stream>>>(edge_rep, src, dst, S);
    build_x0<<<EB, 256, 0, stream>>>(node_rep, S, src, dst, BUF_A);

    // ---- e0 MLP ----
    gemm_bn<256><<<gE2, 256, 0, stream>>>(BUF_A, Wt_e0_1, BUF_B, stats + 0 * 512, EDGES, 256);
    bn_finalize<<<1, 256, 0, stream>>>(stats + 0 * 512, e0G1, e0B1, scsh + 0 * 512, 256, invE);
    bn_apply<<<EB, 256, 0, stream>>>(BUF_B, scsh + 0 * 512, 255, 256, (size_t)EDGES * 256);
    gemm_bn<256><<<gE1, 256, 0, stream>>>(BUF_B, Wt_e0_2, BUF_C, stats + 1 * 512, EDGES, 128);
    bn_finalize<<<1, 256, 0, stream>>>(stats + 1 * 512, e0G2, e0B2, scsh + 1 * 512, 128, invE);
    edge_new_k<<<EB, 256, 0, stream>>>(edge_rep, BUF_C, scsh + 1 * 512, eps1, BUF_D);

    // ---- e1 MLP -> edge_out ----
    gemm_bn<128><<<gE2, 256, 0, stream>>>(BUF_D, Wt_e1_1, BUF_A, stats + 2 * 512, EDGES, 256);
    bn_finalize<<<1, 256, 0, stream>>>(stats + 2 * 512, e1G1, e1B1, scsh + 2 * 512, 256, invE);
    bn_apply<<<EB, 256, 0, stream>>>(BUF_A, scsh + 2 * 512, 255, 256, (size_t)EDGES * 256);
    gemm_bn<256><<<gE1, 256, 0, stream>>>(BUF_A, Wt_e1_2, BUF_C, stats + 3 * 512, EDGES, 128);
    bn_finalize<<<1, 256, 0, stream>>>(stats + 3 * 512, e1G2, e1B2, scsh + 3 * 512, 128, invE);
    edge_out_k<<<EB, 256, 0, stream>>>(BUF_C, scsh + 3 * 512,
                                       (float*)d_out + (size_t)NODES * HDIM);

    // ---- e2 MLP -> edge2node scatter ----
    gemm_bn<128><<<gE2, 256, 0, stream>>>(BUF_D, Wt_e2_1, BUF_B, stats + 4 * 512, EDGES, 256);
    bn_finalize<<<1, 256, 0, stream>>>(stats + 4 * 512, e2G1, e2B1, scsh + 4 * 512, 256, invE);
    bn_apply<<<EB, 256, 0, stream>>>(BUF_B, scsh + 4 * 512, 255, 256, (size_t)EDGES * 256);
    gemm_bn<256><<<gE1, 256, 0, stream>>>(BUF_B, Wt_e2_2, BUF_C, stats + 5 * 512, EDGES, 128);
    bn_finalize<<<1, 256, 0, stream>>>(stats + 5 * 512, e2G2, e2B2, scsh + 5 * 512, 128, invE);
    scatter_e2n<<<EB, 256, 0, stream>>>(BUF_C, scsh + 5 * 512, src, dst, An);

    // ---- node MLP ----
    node_in_k<<<EB, 256, 0, stream>>>(node_rep, An, degree, eps2, NI);
    gemm_bn<128><<<gN2, 256, 0, stream>>>(NI, Wt_n_1, H7, stats + 6 * 512, NODES, 256);
    bn_finalize<<<1, 256, 0, stream>>>(stats + 6 * 512, nG1, nB1, scsh + 6 * 512, 256, invN);
    bn_apply<<<EB, 256, 0, stream>>>(H7, scsh + 6 * 512, 255, 256, (size_t)NODES * 256);
    gemm_bn<256><<<gN1, 256, 0, stream>>>(H7, Wt_n_2, H8, stats + 7 * 512, NODES, 128);
    bn_finalize<<<1, 256, 0, stream>>>(stats + 7 * 512, nG2, nB2, scsh + 7 * 512, 128, invN);
    node_out_k<<<EB, 256, 0, stream>>>(H8, scsh + 7 * 512, (float*)d_out);
}

// Round 2
// 2909.866 us; speedup vs baseline: 1.1215x; 1.1215x over previous
//
#include <hip/hip_runtime.h>
#include <hip/hip_bf16.h>
#include <cstdint>

#define EDGES 400000
#define NODES 50000
#define HDIM  128

typedef unsigned short u16;
typedef __bf16 bf16x8 __attribute__((ext_vector_type(8)));
typedef float  f32x4  __attribute__((ext_vector_type(4)));

__device__ __forceinline__ float bf2f(u16 u) {
    union { uint32_t i; float f; } w; w.i = ((uint32_t)u) << 16; return w.f;
}
__device__ __forceinline__ u16 f2bf(float f) {
    union { float f; uint32_t i; } w; w.f = f;
    uint32_t x = w.i;
    uint32_t r = (x + 0x7fffu + ((x >> 16) & 1u)) >> 16;   // RNE
    return (u16)r;
}
// pack 2 f32 -> 2 bf16 (RNE) in one u32 (lo = first element)
__device__ __forceinline__ uint32_t pk_bf16(float lo, float hi) {
    union { float f; uint32_t i; } a, b; a.f = lo; b.f = hi;
    uint32_t rl = (a.i + 0x7fffu + ((a.i >> 16) & 1u)) >> 16;
    uint32_t rh = (b.i + 0x7fffu + ((b.i >> 16) & 1u)) & 0xffff0000u;
    return rl | rh;
}
// unpack u32 (2 bf16) -> 2 f32
__device__ __forceinline__ void unpk2(uint32_t h2, float& lo, float& hi) {
    union { uint32_t i; float f; } a, b;
    a.i = h2 << 16; b.i = h2 & 0xffff0000u; lo = a.f; hi = b.f;
}
// BN+ReLU on one packed pair
__device__ __forceinline__ uint32_t bnrelu2(uint32_t h2, float scl, float sch,
                                            float shl_, float shh) {
    float lo, hi; unpk2(h2, lo, hi);
    return pk_bf16(fmaxf(fmaf(lo, scl, shl_), 0.f),
                   fmaxf(fmaf(hi, sch, shh), 0.f));
}
// BN+ReLU on 8 packed bf16 given coefficient pointers (8 f32 each)
__device__ __forceinline__ uint4 bnrelu8(uint4 v, const float* __restrict__ sc,
                                         const float* __restrict__ sh) {
    float4 s0 = *(const float4*)sc, s1 = *(const float4*)(sc + 4);
    float4 t0 = *(const float4*)sh, t1 = *(const float4*)(sh + 4);
    v.x = bnrelu2(v.x, s0.x, s0.y, t0.x, t0.y);
    v.y = bnrelu2(v.y, s0.z, s0.w, t0.z, t0.w);
    v.z = bnrelu2(v.z, s1.x, s1.y, t1.x, t1.y);
    v.w = bnrelu2(v.w, s1.z, s1.w, t1.z, t1.w);
    return v;
}

// ---------------------------------------------------------------------------
// Weight convert + transpose: W[k][n] f32  ->  Wt[n][k] bf16
// ---------------------------------------------------------------------------
__global__ void wt_convert(const float* __restrict__ W, u16* __restrict__ Wt,
                           int K, int Nout) {
    int idx = blockIdx.x * 256 + threadIdx.x;
    if (idx < K * Nout) {
        int n = idx / K, k = idx - n * K;
        Wt[idx] = f2bf(W[(size_t)k * Nout + n]);
    }
}

// ---------------------------------------------------------------------------
// S[n][h] = sum over incident edges (atomic f32, coalesced per row)
// ---------------------------------------------------------------------------
__global__ void scatter_S(const float* __restrict__ edge_rep,
                          const int* __restrict__ src, const int* __restrict__ dst,
                          float* __restrict__ S) {
    size_t stride = (size_t)gridDim.x * blockDim.x;
    for (size_t i = (size_t)blockIdx.x * blockDim.x + threadIdx.x;
         i < (size_t)EDGES * HDIM; i += stride) {
        int e = (int)(i >> 7), h = (int)(i & 127);
        float v = edge_rep[i];
        atomicAdd(&S[(size_t)src[e] * HDIM + h], v);
        atomicAdd(&S[(size_t)dst[e] * HDIM + h], v);
    }
}

// X0[e][0:128] = node[src]+node[dst]; X0[e][128:256] = S[src]+S[dst]  (8-wide)
__global__ void build_x0_v(const float* __restrict__ node_rep, const float* __restrict__ S,
                           const int* __restrict__ src, const int* __restrict__ dst,
                           u16* __restrict__ X0) {
    size_t stride = (size_t)gridDim.x * blockDim.x;
    for (size_t t = (size_t)blockIdx.x * blockDim.x + threadIdx.x;
         t < (size_t)EDGES * 16; t += stride) {
        int e  = (int)(t >> 4);
        int h8 = (int)(t & 15) * 8;
        size_t so = (size_t)src[e] * HDIM + h8;
        size_t dv = (size_t)dst[e] * HDIM + h8;
        float4 a0 = *(const float4*)&node_rep[so], a1 = *(const float4*)&node_rep[so + 4];
        float4 b0 = *(const float4*)&node_rep[dv], b1 = *(const float4*)&node_rep[dv + 4];
        float4 c0 = *(const float4*)&S[so],        c1 = *(const float4*)&S[so + 4];
        float4 d0 = *(const float4*)&S[dv],        d1 = *(const float4*)&S[dv + 4];
        uint4 o1, o2;
        o1.x = pk_bf16(a0.x + b0.x, a0.y + b0.y);
        o1.y = pk_bf16(a0.z + b0.z, a0.w + b0.w);
        o1.z = pk_bf16(a1.x + b1.x, a1.y + b1.y);
        o1.w = pk_bf16(a1.z + b1.z, a1.w + b1.w);
        o2.x = pk_bf16(c0.x + d0.x, c0.y + d0.y);
        o2.y = pk_bf16(c0.z + d0.z, c0.w + d0.w);
        o2.z = pk_bf16(c1.x + d1.x, c1.y + d1.y);
        o2.w = pk_bf16(c1.z + d1.z, c1.w + d1.w);
        *(uint4*)&X0[(size_t)e * 256 + h8]       = o1;
        *(uint4*)&X0[(size_t)e * 256 + 128 + h8] = o2;
    }
}

// ---------------------------------------------------------------------------
// GEMM: Out[M,Nout](bf16) = A[M,K] @ Wt[Nout,K]^T, f32 accum, col-stats epi.
// FUSE: apply y=relu(x*sc+sh) to A during staging (coeff indexed by k).
// ---------------------------------------------------------------------------
template<int K, bool FUSE>
__global__ __launch_bounds__(256) void gemm_bn(
    const u16* __restrict__ A, const u16* __restrict__ Wt,
    u16* __restrict__ Out, float* __restrict__ stats, int M, int Nout,
    const float* __restrict__ fsc)
{
    __shared__ u16 Al[128][72];   // +8 pad: row pitch 144B -> 2-way bank alias (free)
    __shared__ u16 Bl[128][72];
    const int tid  = threadIdx.x;
    const int lane = tid & 63;
    const int w    = tid >> 6;
    const int wrow = w >> 1, wcol = w & 1;
    const int mrow0 = blockIdx.x * 128;
    const int ncol0 = blockIdx.y * 128;
    f32x4 acc[4][4] = {};

    const int srow = tid >> 3;          // 0..31
    const int sc8  = (tid & 7) * 8;     // 0..56

    for (int k0 = 0; k0 < K; k0 += 64) {
        if (k0) __syncthreads();
        #pragma unroll
        for (int p = 0; p < 4; ++p) {
            int row  = srow + p * 32;
            int grow = mrow0 + row;
            uint4 va = make_uint4(0u, 0u, 0u, 0u);
            if (grow < M) {
                va = *reinterpret_cast<const uint4*>(&A[(size_t)grow * K + k0 + sc8]);
                if (FUSE)   // padded rows stay exact zero -> stats exact
                    va = bnrelu8(va, &fsc[k0 + sc8], &fsc[K + k0 + sc8]);
            }
            *reinterpret_cast<uint4*>(&Al[row][sc8]) = va;
            uint4 vb = *reinterpret_cast<const uint4*>(&Wt[(size_t)(ncol0 + row) * K + k0 + sc8]);
            *reinterpret_cast<uint4*>(&Bl[row][sc8]) = vb;
        }
        __syncthreads();
        #pragma unroll
        for (int kk = 0; kk < 64; kk += 32) {
            const int lr = lane & 15;
            const int kc = kk + (lane >> 4) * 8;
            bf16x8 af[4], bfr[4];
            #pragma unroll
            for (int m = 0; m < 4; ++m)
                af[m] = *reinterpret_cast<const bf16x8*>(&Al[wrow * 64 + m * 16 + lr][kc]);
            #pragma unroll
            for (int n = 0; n < 4; ++n)
                bfr[n] = *reinterpret_cast<const bf16x8*>(&Bl[wcol * 64 + n * 16 + lr][kc]);
            #pragma unroll
            for (int m = 0; m < 4; ++m)
                #pragma unroll
                for (int n = 0; n < 4; ++n)
                    acc[m][n] = __builtin_amdgcn_mfma_f32_16x16x32_bf16(
                        af[m], bfr[n], acc[m][n], 0, 0, 0);
        }
    }

    const int lr = lane & 15, lq = lane >> 4;
    // C-store  -- verified C/D layout: col=lane&15, row=(lane>>4)*4+i
    #pragma unroll
    for (int m = 0; m < 4; ++m) {
        #pragma unroll
        for (int n = 0; n < 4; ++n) {
            int col = ncol0 + wcol * 64 + n * 16 + lr;
            #pragma unroll
            for (int i = 0; i < 4; ++i) {
                int row = mrow0 + wrow * 64 + m * 16 + lq * 4 + i;
                if (row < M)
                    Out[(size_t)row * Nout + col] = f2bf(acc[m][n][i]);
            }
        }
    }
    // column stats (padded rows are exact zeros -> contribute nothing)
    #pragma unroll
    for (int n = 0; n < 4; ++n) {
        float s = 0.f, q = 0.f;
        #pragma unroll
        for (int m = 0; m < 4; ++m)
            #pragma unroll
            for (int i = 0; i < 4; ++i) { float v = acc[m][n][i]; s += v; q += v * v; }
        s += __shfl_xor(s, 16); s += __shfl_xor(s, 32);
        q += __shfl_xor(q, 16); q += __shfl_xor(q, 32);
        if (lq == 0) {
            int col = ncol0 + wcol * 64 + n * 16 + lr;
            atomicAdd(&stats[col], s);
            atomicAdd(&stats[Nout + col], q);
        }
    }
}

// scsh[j] = g/sqrt(var+eps); scsh[Nout+j] = b - mean*scale
__global__ void bn_finalize(const float* __restrict__ stats, const float* __restrict__ G,
                            const float* __restrict__ Bi, float* __restrict__ scsh,
                            int Nout, float invM) {
    int j = threadIdx.x;
    if (j < Nout) {
        float mean = stats[j] * invM;
        float var  = stats[Nout + j] * invM - mean * mean;
        float sc   = G[j] / sqrtf(var + 1e-5f);
        scsh[j]        = sc;
        scsh[Nout + j] = Bi[j] - mean * sc;
    }
}

// EN = (1+eps1)*edge_rep + relu(H2*s+t)   (8-wide, bf16 out)
__global__ void edge_new_v(const float* __restrict__ edge_rep, const u16* __restrict__ H2,
                           const float* __restrict__ scsh, const float* __restrict__ eps1,
                           u16* __restrict__ EN) {
    float e1 = 1.0f + eps1[0];
    size_t stride = (size_t)gridDim.x * blockDim.x;
    for (size_t t = (size_t)blockIdx.x * blockDim.x + threadIdx.x;
         t < (size_t)EDGES * 16; t += stride) {
        size_t base = t * 8;
        int h8 = (int)(t & 15) * 8;
        uint4 h = *(const uint4*)&H2[base];
        h = bnrelu8(h, &scsh[h8], &scsh[128 + h8]);       // relu(H2*s+t) in bf16
        float4 r0 = *(const float4*)&edge_rep[base];
        float4 r1 = *(const float4*)&edge_rep[base + 4];
        float m0, m1, m2, m3, m4, m5, m6, m7;
        unpk2(h.x, m0, m1); unpk2(h.y, m2, m3);
        unpk2(h.z, m4, m5); unpk2(h.w, m6, m7);
        uint4 o;
        o.x = pk_bf16(fmaf(e1, r0.x, m0), fmaf(e1, r0.y, m1));
        o.y = pk_bf16(fmaf(e1, r0.z, m2), fmaf(e1, r0.w, m3));
        o.z = pk_bf16(fmaf(e1, r1.x, m4), fmaf(e1, r1.y, m5));
        o.w = pk_bf16(fmaf(e1, r1.z, m6), fmaf(e1, r1.w, m7));
        *(uint4*)&EN[base] = o;
    }
}

// out(f32) = relu(H*s+t)   (8-wide), Nout=128
__global__ void affine_out_v(const u16* __restrict__ H, const float* __restrict__ scsh,
                             float* __restrict__ out, size_t t16) {
    size_t stride = (size_t)gridDim.x * blockDim.x;
    for (size_t t = (size_t)blockIdx.x * blockDim.x + threadIdx.x; t < t16; t += stride) {
        size_t base = t * 8;
        int h8 = (int)(t & 15) * 8;
        uint4 h = *(const uint4*)&H[base];
        float4 s0 = *(const float4*)&scsh[h8],       s1 = *(const float4*)&scsh[h8 + 4];
        float4 t0 = *(const float4*)&scsh[128 + h8], t1 = *(const float4*)&scsh[128 + h8 + 4];
        float v0, v1, v2, v3, v4, v5, v6, v7;
        unpk2(h.x, v0, v1); unpk2(h.y, v2, v3);
        unpk2(h.z, v4, v5); unpk2(h.w, v6, v7);
        float4 o0, o1;
        o0.x = fmaxf(fmaf(v0, s0.x, t0.x), 0.f);
        o0.y = fmaxf(fmaf(v1, s0.y, t0.y), 0.f);
        o0.z = fmaxf(fmaf(v2, s0.z, t0.z), 0.f);
        o0.w = fmaxf(fmaf(v3, s0.w, t0.w), 0.f);
        o1.x = fmaxf(fmaf(v4, s1.x, t1.x), 0.f);
        o1.y = fmaxf(fmaf(v5, s1.y, t1.y), 0.f);
        o1.z = fmaxf(fmaf(v6, s1.z, t1.z), 0.f);
        o1.w = fmaxf(fmaf(v7, s1.w, t1.w), 0.f);
        *(float4*)&out[base]     = o0;
        *(float4*)&out[base + 4] = o1;
    }
}

// An[src] += relu(H6*s+t); An[dst] += ...   (atomic, coalesced per row)
__global__ void scatter_e2n(const u16* __restrict__ H6, const float* __restrict__ scsh,
                            const int* __restrict__ src, const int* __restrict__ dst,
                            float* __restrict__ An) {
    size_t stride = (size_t)gridDim.x * blockDim.x;
    for (size_t i = (size_t)blockIdx.x * blockDim.x + threadIdx.x;
         i < (size_t)EDGES * HDIM; i += stride) {
        int e = (int)(i >> 7), h = (int)(i & 127);
        float m = fmaxf(bf2f(H6[i]) * scsh[h] + scsh[128 + h], 0.f);
        atomicAdd(&An[(size_t)src[e] * HDIM + h], m);
        atomicAdd(&An[(size_t)dst[e] * HDIM + h], m);
    }
}

// NI = bf16((1+eps2-degree)*node_rep + An)   (8-wide)
__global__ void node_in_v(const float* __restrict__ node_rep, const float* __restrict__ An,
                          const float* __restrict__ degree, const float* __restrict__ eps2,
                          u16* __restrict__ NI) {
    float e2 = 1.0f + eps2[0];
    size_t stride = (size_t)gridDim.x * blockDim.x;
    for (size_t t = (size_t)blockIdx.x * blockDim.x + threadIdx.x;
         t < (size_t)NODES * 16; t += stride) {
        int n = (int)(t >> 4);
        size_t base = t * 8;
        float c = e2 - degree[n];
        float4 r0 = *(const float4*)&node_rep[base], r1 = *(const float4*)&node_rep[base + 4];
        float4 a0 = *(const float4*)&An[base],       a1 = *(const float4*)&An[base + 4];
        uint4 o;
        o.x = pk_bf16(fmaf(c, r0.x, a0.x), fmaf(c, r0.y, a0.y));
        o.y = pk_bf16(fmaf(c, r0.z, a0.z), fmaf(c, r0.w, a0.w));
        o.z = pk_bf16(fmaf(c, r1.x, a1.x), fmaf(c, r1.y, a1.y));
        o.w = pk_bf16(fmaf(c, r1.z, a1.z), fmaf(c, r1.w, a1.w));
        *(uint4*)&NI[base] = o;
    }
}

// ---------------------------------------------------------------------------
extern "C" void kernel_launch(void* const* d_in, const int* in_sizes, int n_in,
                              void* d_out, int out_size, void* d_ws, size_t ws_size,
                              hipStream_t stream) {
    const float* node_rep = (const float*)d_in[0];
    const float* edge_rep = (const float*)d_in[1];
    const float* degree   = (const float*)d_in[2];
    const int*   src      = (const int*)d_in[3];
    const int*   dst      = (const int*)d_in[4];
    const float* eps1     = (const float*)d_in[5];
    const float* eps2     = (const float*)d_in[6];
    const float* nW1  = (const float*)d_in[7];
    const float* nG1  = (const float*)d_in[8];
    const float* nB1  = (const float*)d_in[9];
    const float* nW2  = (const float*)d_in[10];
    const float* nG2  = (const float*)d_in[11];
    const float* nB2  = (const float*)d_in[12];
    const float* e0W1 = (const float*)d_in[13];
    const float* e0G1 = (const float*)d_in[14];
    const float* e0B1 = (const float*)d_in[15];
    const float* e0W2 = (const float*)d_in[16];
    const float* e0G2 = (const float*)d_in[17];
    const float* e0B2 = (const float*)d_in[18];
    const float* e1W1 = (const float*)d_in[19];
    const float* e1G1 = (const float*)d_in[20];
    const float* e1B1 = (const float*)d_in[21];
    const float* e1W2 = (const float*)d_in[22];
    const float* e1G2 = (const float*)d_in[23];
    const float* e1B2 = (const float*)d_in[24];
    const float* e2W1 = (const float*)d_in[25];
    const float* e2G1 = (const float*)d_in[26];
    const float* e2B1 = (const float*)d_in[27];
    const float* e2W2 = (const float*)d_in[28];
    const float* e2G2 = (const float*)d_in[29];
    const float* e2B2 = (const float*)d_in[30];

    // ---- workspace layout (all 256B aligned) ----
    size_t off = 0;
    auto alloc = [&](size_t bytes) -> void* {
        void* p = (char*)d_ws + off;
        off += (bytes + 255) & ~(size_t)255;
        return p;
    };
    u16*   BUF_A = (u16*)alloc((size_t)EDGES * 256 * 2);   // X0 -> H3
    u16*   BUF_B = (u16*)alloc((size_t)EDGES * 256 * 2);   // H1 -> H5
    u16*   BUF_C = (u16*)alloc((size_t)EDGES * 128 * 2);   // H2 -> H4 -> H6
    u16*   BUF_D = (u16*)alloc((size_t)EDGES * 128 * 2);   // edge_new
    float* S     = (float*)alloc((size_t)NODES * 128 * 4);
    float* An    = (float*)alloc((size_t)NODES * 128 * 4);
    u16*   NI    = (u16*)alloc((size_t)NODES * 128 * 2);
    u16*   H7    = (u16*)alloc((size_t)NODES * 256 * 2);
    u16*   H8    = (u16*)alloc((size_t)NODES * 128 * 2);
    u16* Wt_e0_1 = (u16*)alloc(256 * 256 * 2);
    u16* Wt_e0_2 = (u16*)alloc(128 * 256 * 2);
    u16* Wt_e1_1 = (u16*)alloc(256 * 128 * 2);
    u16* Wt_e1_2 = (u16*)alloc(128 * 256 * 2);
    u16* Wt_e2_1 = (u16*)alloc(256 * 128 * 2);
    u16* Wt_e2_2 = (u16*)alloc(128 * 256 * 2);
    u16* Wt_n_1  = (u16*)alloc(256 * 128 * 2);
    u16* Wt_n_2  = (u16*)alloc(128 * 256 * 2);
    float* stats = (float*)alloc(8 * 512 * 4);
    float* scsh  = (float*)alloc(8 * 512 * 4);
    if (off > ws_size) return;

    hipMemsetAsync(S,     0, (size_t)NODES * 128 * 4, stream);
    hipMemsetAsync(An,    0, (size_t)NODES * 128 * 4, stream);
    hipMemsetAsync(stats, 0, 8 * 512 * 4, stream);

    const int EB  = 8192;   // grid-stride blocks, scalar E*128 loops (scatter)
    const int EV  = 4096;   // 8-wide E*16 loops
    const int NV  = 3125;   // 8-wide NODES*16 loops (exact)
    const float invE = 1.0f / (float)EDGES;
    const float invN = 1.0f / (float)NODES;
    const dim3 gE2(3125, 2), gE1(3125, 1), gN2(391, 2), gN1(391, 1);

    // weights -> bf16 transposed
    wt_convert<<<(256 * 256 + 255) / 256, 256, 0, stream>>>(e0W1, Wt_e0_1, 256, 256);
    wt_convert<<<(128 * 256 + 255) / 256, 256, 0, stream>>>(e0W2, Wt_e0_2, 256, 128);
    wt_convert<<<(256 * 128 + 255) / 256, 256, 0, stream>>>(e1W1, Wt_e1_1, 128, 256);
    wt_convert<<<(128 * 256 + 255) / 256, 256, 0, stream>>>(e1W2, Wt_e1_2, 256, 128);
    wt_convert<<<(256 * 128 + 255) / 256, 256, 0, stream>>>(e2W1, Wt_e2_1, 128, 256);
    wt_convert<<<(128 * 256 + 255) / 256, 256, 0, stream>>>(e2W2, Wt_e2_2, 256, 128);
    wt_convert<<<(256 * 128 + 255) / 256, 256, 0, stream>>>(nW1, Wt_n_1, 128, 256);
    wt_convert<<<(128 * 256 + 255) / 256, 256, 0, stream>>>(nW2, Wt_n_2, 256, 128);

    // graph gathers
    scatter_S<<<EB, 256, 0, stream>>>(edge_rep, src, dst, S);
    build_x0_v<<<EV, 256, 0, stream>>>(node_rep, S, src, dst, BUF_A);

    // ---- e0 MLP ----
    gemm_bn<256, false><<<gE2, 256, 0, stream>>>(BUF_A, Wt_e0_1, BUF_B, stats + 0 * 512, EDGES, 256, nullptr);
    bn_finalize<<<1, 256, 0, stream>>>(stats + 0 * 512, e0G1, e0B1, scsh + 0 * 512, 256, invE);
    gemm_bn<256, true><<<gE1, 256, 0, stream>>>(BUF_B, Wt_e0_2, BUF_C, stats + 1 * 512, EDGES, 128, scsh + 0 * 512);
    bn_finalize<<<1, 256, 0, stream>>>(stats + 1 * 512, e0G2, e0B2, scsh + 1 * 512, 128, invE);
    edge_new_v<<<EV, 256, 0, stream>>>(edge_rep, BUF_C, scsh + 1 * 512, eps1, BUF_D);

    // ---- e1 MLP -> edge_out ----
    gemm_bn<128, false><<<gE2, 256, 0, stream>>>(BUF_D, Wt_e1_1, BUF_A, stats + 2 * 512, EDGES, 256, nullptr);
    bn_finalize<<<1, 256, 0, stream>>>(stats + 2 * 512, e1G1, e1B1, scsh + 2 * 512, 256, invE);
    gemm_bn<256, true><<<gE1, 256, 0, stream>>>(BUF_A, Wt_e1_2, BUF_C, stats + 3 * 512, EDGES, 128, scsh + 2 * 512);
    bn_finalize<<<1, 256, 0, stream>>>(stats + 3 * 512, e1G2, e1B2, scsh + 3 * 512, 128, invE);
    affine_out_v<<<EV, 256, 0, stream>>>(BUF_C, scsh + 3 * 512,
                                         (float*)d_out + (size_t)NODES * HDIM,
                                         (size_t)EDGES * 16);

    // ---- e2 MLP -> edge2node scatter ----
    gemm_bn<128, false><<<gE2, 256, 0, stream>>>(BUF_D, Wt_e2_1, BUF_B, stats + 4 * 512, EDGES, 256, nullptr);
    bn_finalize<<<1, 256, 0, stream>>>(stats + 4 * 512, e2G1, e2B1, scsh + 4 * 512, 256, invE);
    gemm_bn<256, true><<<gE1, 256, 0, stream>>>(BUF_B, Wt_e2_2, BUF_C, stats + 5 * 512, EDGES, 128, scsh + 4 * 512);
    bn_finalize<<<1, 256, 0, stream>>>(stats + 5 * 512, e2G2, e2B2, scsh + 5 * 512, 128, invE);
    scatter_e2n<<<EB, 256, 0, stream>>>(BUF_C, scsh + 5 * 512, src, dst, An);

    // ---- node MLP ----
    node_in_v<<<NV, 256, 0, stream>>>(node_rep, An, degree, eps2, NI);
    gemm_bn<128, false><<<gN2, 256, 0, stream>>>(NI, Wt_n_1, H7, stats + 6 * 512, NODES, 256, nullptr);
    bn_finalize<<<1, 256, 0, stream>>>(stats + 6 * 512, nG1, nB1, scsh + 6 * 512, 256, invN);
    gemm_bn<256, true><<<gN1, 256, 0, stream>>>(H7, Wt_n_2, H8, stats + 7 * 512, NODES, 128, scsh + 6 * 512);
    bn_finalize<<<1, 256, 0, stream>>>(stats + 7 * 512, nG2, nB2, scsh + 7 * 512, 128, invN);
    affine_out_v<<<NV, 256, 0, stream>>>(H8, scsh + 7 * 512, (float*)d_out,
                                         (size_t)NODES * 16);
}

// Round 3
// 2814.542 us; speedup vs baseline: 1.1595x; 1.0339x over previous
//
#include <hip/hip_runtime.h>
#include <hip/hip_bf16.h>
#include <cstdint>

#define EDGES 400000
#define NODES 50000
#define HDIM  128

typedef unsigned short u16;
typedef __bf16 bf16x8 __attribute__((ext_vector_type(8)));
typedef float  f32x4  __attribute__((ext_vector_type(4)));

__device__ __forceinline__ float bf2f(u16 u) {
    union { uint32_t i; float f; } w; w.i = ((uint32_t)u) << 16; return w.f;
}
__device__ __forceinline__ u16 f2bf(float f) {
    union { float f; uint32_t i; } w; w.f = f;
    uint32_t x = w.i;
    uint32_t r = (x + 0x7fffu + ((x >> 16) & 1u)) >> 16;   // RNE
    return (u16)r;
}
// pack 2 f32 -> 2 bf16 (RNE) in one u32 (lo = first element)
__device__ __forceinline__ uint32_t pk_bf16(float lo, float hi) {
    union { float f; uint32_t i; } a, b; a.f = lo; b.f = hi;
    uint32_t rl = (a.i + 0x7fffu + ((a.i >> 16) & 1u)) >> 16;
    uint32_t rh = (b.i + 0x7fffu + ((b.i >> 16) & 1u)) & 0xffff0000u;
    return rl | rh;
}
// unpack u32 (2 bf16) -> 2 f32
__device__ __forceinline__ void unpk2(uint32_t h2, float& lo, float& hi) {
    union { uint32_t i; float f; } a, b;
    a.i = h2 << 16; b.i = h2 & 0xffff0000u; lo = a.f; hi = b.f;
}
// BN+ReLU on one packed pair
__device__ __forceinline__ uint32_t bnrelu2(uint32_t h2, float scl, float sch,
                                            float shl_, float shh) {
    float lo, hi; unpk2(h2, lo, hi);
    return pk_bf16(fmaxf(fmaf(lo, scl, shl_), 0.f),
                   fmaxf(fmaf(hi, sch, shh), 0.f));
}
// BN+ReLU on 8 packed bf16 given coefficient pointers (8 f32 each)
__device__ __forceinline__ uint4 bnrelu8(uint4 v, const float* __restrict__ sc,
                                         const float* __restrict__ sh) {
    float4 s0 = *(const float4*)sc, s1 = *(const float4*)(sc + 4);
    float4 t0 = *(const float4*)sh, t1 = *(const float4*)(sh + 4);
    v.x = bnrelu2(v.x, s0.x, s0.y, t0.x, t0.y);
    v.y = bnrelu2(v.y, s0.z, s0.w, t0.z, t0.w);
    v.z = bnrelu2(v.z, s1.x, s1.y, t1.x, t1.y);
    v.w = bnrelu2(v.w, s1.z, s1.w, t1.z, t1.w);
    return v;
}

// async global(16B/lane) -> LDS, wave-uniform LDS base + lane*16 (m97 pattern)
__device__ __forceinline__ void gload16(const u16* g, u16* l) {
    __builtin_amdgcn_global_load_lds(
        (const __attribute__((address_space(1))) void*)(const void*)g,
        (__attribute__((address_space(3))) void*)(void*)l, 16, 0, 0);
}

// ---------------------------------------------------------------------------
// Weight convert + transpose: W[k][n] f32  ->  Wt[n][k] bf16
// ---------------------------------------------------------------------------
__global__ void wt_convert(const float* __restrict__ W, u16* __restrict__ Wt,
                           int K, int Nout) {
    int idx = blockIdx.x * 256 + threadIdx.x;
    if (idx < K * Nout) {
        int n = idx / K, k = idx - n * K;
        Wt[idx] = f2bf(W[(size_t)k * Nout + n]);
    }
}

// ---------------------------------------------------------------------------
// S[n][h] = sum over incident edges (atomic f32, coalesced per row)
// ---------------------------------------------------------------------------
__global__ void scatter_S(const float* __restrict__ edge_rep,
                          const int* __restrict__ src, const int* __restrict__ dst,
                          float* __restrict__ S) {
    size_t stride = (size_t)gridDim.x * blockDim.x;
    for (size_t i = (size_t)blockIdx.x * blockDim.x + threadIdx.x;
         i < (size_t)EDGES * HDIM; i += stride) {
        int e = (int)(i >> 7), h = (int)(i & 127);
        float v = edge_rep[i];
        atomicAdd(&S[(size_t)src[e] * HDIM + h], v);
        atomicAdd(&S[(size_t)dst[e] * HDIM + h], v);
    }
}

// X0[e][0:128] = node[src]+node[dst]; X0[e][128:256] = S[src]+S[dst]  (8-wide)
__global__ void build_x0_v(const float* __restrict__ node_rep, const float* __restrict__ S,
                           const int* __restrict__ src, const int* __restrict__ dst,
                           u16* __restrict__ X0) {
    size_t stride = (size_t)gridDim.x * blockDim.x;
    for (size_t t = (size_t)blockIdx.x * blockDim.x + threadIdx.x;
         t < (size_t)EDGES * 16; t += stride) {
        int e  = (int)(t >> 4);
        int h8 = (int)(t & 15) * 8;
        size_t so = (size_t)src[e] * HDIM + h8;
        size_t dv = (size_t)dst[e] * HDIM + h8;
        float4 a0 = *(const float4*)&node_rep[so], a1 = *(const float4*)&node_rep[so + 4];
        float4 b0 = *(const float4*)&node_rep[dv], b1 = *(const float4*)&node_rep[dv + 4];
        float4 c0 = *(const float4*)&S[so],        c1 = *(const float4*)&S[so + 4];
        float4 d0 = *(const float4*)&S[dv],        d1 = *(const float4*)&S[dv + 4];
        uint4 o1, o2;
        o1.x = pk_bf16(a0.x + b0.x, a0.y + b0.y);
        o1.y = pk_bf16(a0.z + b0.z, a0.w + b0.w);
        o1.z = pk_bf16(a1.x + b1.x, a1.y + b1.y);
        o1.w = pk_bf16(a1.z + b1.z, a1.w + b1.w);
        o2.x = pk_bf16(c0.x + d0.x, c0.y + d0.y);
        o2.y = pk_bf16(c0.z + d0.z, c0.w + d0.w);
        o2.z = pk_bf16(c1.x + d1.x, c1.y + d1.y);
        o2.w = pk_bf16(c1.z + d1.z, c1.w + d1.w);
        *(uint4*)&X0[(size_t)e * 256 + h8]       = o1;
        *(uint4*)&X0[(size_t)e * 256 + 128 + h8] = o2;
    }
}

// ---------------------------------------------------------------------------
// GEMM: Out[M,Nout](bf16) = A[M,K] @ Wt[Nout,K]^T, f32 accum, col-stats epi.
// Staging: global_load_lds (16B/lane) into linear LDS for B always and for A
// when !FUSE (caller guarantees A rows padded to x128 with zeros).
// FUSE: A reg-staged with y=relu(x*sc+sh) applied (pad rows stay exact zero).
// ---------------------------------------------------------------------------
template<int K, bool FUSE>
__global__ __launch_bounds__(256, 4) void gemm_bn(
    const u16* __restrict__ A, const u16* __restrict__ Wt,
    u16* __restrict__ Out, float* __restrict__ stats, int M, int Nout,
    const float* __restrict__ fsc)
{
    __shared__ u16 Al[128][64];   // linear: global_load_lds needs contiguous dest
    __shared__ u16 Bl[128][64];
    const int tid  = threadIdx.x;
    const int lane = tid & 63;
    const int w    = tid >> 6;
    const int wrow = w >> 1, wcol = w & 1;
    const int mrow0 = blockIdx.x * 128;
    const int ncol0 = blockIdx.y * 128;
    f32x4 acc[4][4] = {};

    const int srow = tid >> 3;          // 0..31 (reg-staged path)
    const int sc8  = (tid & 7) * 8;     // 0..56
    const int crow = lane >> 3;         // 0..7  (gload chunk-local row)
    const int cc8  = (lane & 7) * 8;    // 0..56

    for (int k0 = 0; k0 < K; k0 += 64) {
        if (k0) __syncthreads();
        // ---- B tile: always async direct-to-LDS ----
        #pragma unroll
        for (int ch = w; ch < 16; ch += 4) {
            int row = ch * 8 + crow;
            gload16(&Wt[(size_t)(ncol0 + row) * K + k0 + cc8], &Bl[ch * 8][0]);
        }
        if (!FUSE) {
            #pragma unroll
            for (int ch = w; ch < 16; ch += 4) {
                int row = ch * 8 + crow;
                gload16(&A[(size_t)(mrow0 + row) * K + k0 + cc8], &Al[ch * 8][0]);
            }
        } else {
            #pragma unroll
            for (int p = 0; p < 4; ++p) {
                int row  = srow + p * 32;
                int grow = mrow0 + row;
                uint4 va = make_uint4(0u, 0u, 0u, 0u);
                if (grow < M) {
                    va = *reinterpret_cast<const uint4*>(&A[(size_t)grow * K + k0 + sc8]);
                    va = bnrelu8(va, &fsc[k0 + sc8], &fsc[K + k0 + sc8]);
                }
                *reinterpret_cast<uint4*>(&Al[row][sc8]) = va;
            }
        }
        __syncthreads();
        #pragma unroll
        for (int kk = 0; kk < 64; kk += 32) {
            const int lr = lane & 15;
            const int kc = kk + (lane >> 4) * 8;
            bf16x8 af[4], bfr[4];
            #pragma unroll
            for (int m = 0; m < 4; ++m)
                af[m] = *reinterpret_cast<const bf16x8*>(&Al[wrow * 64 + m * 16 + lr][kc]);
            #pragma unroll
            for (int n = 0; n < 4; ++n)
                bfr[n] = *reinterpret_cast<const bf16x8*>(&Bl[wcol * 64 + n * 16 + lr][kc]);
            #pragma unroll
            for (int m = 0; m < 4; ++m)
                #pragma unroll
                for (int n = 0; n < 4; ++n)
                    acc[m][n] = __builtin_amdgcn_mfma_f32_16x16x32_bf16(
                        af[m], bfr[n], acc[m][n], 0, 0, 0);
        }
    }

    const int lr = lane & 15, lq = lane >> 4;
    // C-store  -- verified C/D layout: col=lane&15, row=(lane>>4)*4+i
    #pragma unroll
    for (int m = 0; m < 4; ++m) {
        #pragma unroll
        for (int n = 0; n < 4; ++n) {
            int col = ncol0 + wcol * 64 + n * 16 + lr;
            #pragma unroll
            for (int i = 0; i < 4; ++i) {
                int row = mrow0 + wrow * 64 + m * 16 + lq * 4 + i;
                if (row < M)
                    Out[(size_t)row * Nout + col] = f2bf(acc[m][n][i]);
            }
        }
    }
    // column stats (pad rows are exact zeros -> contribute nothing)
    #pragma unroll
    for (int n = 0; n < 4; ++n) {
        float s = 0.f, q = 0.f;
        #pragma unroll
        for (int m = 0; m < 4; ++m)
            #pragma unroll
            for (int i = 0; i < 4; ++i) { float v = acc[m][n][i]; s += v; q += v * v; }
        s += __shfl_xor(s, 16); s += __shfl_xor(s, 32);
        q += __shfl_xor(q, 16); q += __shfl_xor(q, 32);
        if (lq == 0) {
            int col = ncol0 + wcol * 64 + n * 16 + lr;
            atomicAdd(&stats[col], s);
            atomicAdd(&stats[Nout + col], q);
        }
    }
}

// scsh[j] = g/sqrt(var+eps); scsh[Nout+j] = b - mean*scale
__global__ void bn_finalize(const float* __restrict__ stats, const float* __restrict__ G,
                            const float* __restrict__ Bi, float* __restrict__ scsh,
                            int Nout, float invM) {
    int j = threadIdx.x;
    if (j < Nout) {
        float mean = stats[j] * invM;
        float var  = stats[Nout + j] * invM - mean * mean;
        float sc   = G[j] / sqrtf(var + 1e-5f);
        scsh[j]        = sc;
        scsh[Nout + j] = Bi[j] - mean * sc;
    }
}

// EN = (1+eps1)*edge_rep + relu(H2*s+t)   (8-wide, bf16 out)
__global__ void edge_new_v(const float* __restrict__ edge_rep, const u16* __restrict__ H2,
                           const float* __restrict__ scsh, const float* __restrict__ eps1,
                           u16* __restrict__ EN) {
    float e1 = 1.0f + eps1[0];
    size_t stride = (size_t)gridDim.x * blockDim.x;
    for (size_t t = (size_t)blockIdx.x * blockDim.x + threadIdx.x;
         t < (size_t)EDGES * 16; t += stride) {
        size_t base = t * 8;
        int h8 = (int)(t & 15) * 8;
        uint4 h = *(const uint4*)&H2[base];
        h = bnrelu8(h, &scsh[h8], &scsh[128 + h8]);       // relu(H2*s+t) in bf16
        float4 r0 = *(const float4*)&edge_rep[base];
        float4 r1 = *(const float4*)&edge_rep[base + 4];
        float m0, m1, m2, m3, m4, m5, m6, m7;
        unpk2(h.x, m0, m1); unpk2(h.y, m2, m3);
        unpk2(h.z, m4, m5); unpk2(h.w, m6, m7);
        uint4 o;
        o.x = pk_bf16(fmaf(e1, r0.x, m0), fmaf(e1, r0.y, m1));
        o.y = pk_bf16(fmaf(e1, r0.z, m2), fmaf(e1, r0.w, m3));
        o.z = pk_bf16(fmaf(e1, r1.x, m4), fmaf(e1, r1.y, m5));
        o.w = pk_bf16(fmaf(e1, r1.z, m6), fmaf(e1, r1.w, m7));
        *(uint4*)&EN[base] = o;
    }
}

// out(f32) = relu(H*s+t)   (8-wide), Nout=128
__global__ void affine_out_v(const u16* __restrict__ H, const float* __restrict__ scsh,
                             float* __restrict__ out, size_t t16) {
    size_t stride = (size_t)gridDim.x * blockDim.x;
    for (size_t t = (size_t)blockIdx.x * blockDim.x + threadIdx.x; t < t16; t += stride) {
        size_t base = t * 8;
        int h8 = (int)(t & 15) * 8;
        uint4 h = *(const uint4*)&H[base];
        float4 s0 = *(const float4*)&scsh[h8],       s1 = *(const float4*)&scsh[h8 + 4];
        float4 t0 = *(const float4*)&scsh[128 + h8], t1 = *(const float4*)&scsh[128 + h8 + 4];
        float v0, v1, v2, v3, v4, v5, v6, v7;
        unpk2(h.x, v0, v1); unpk2(h.y, v2, v3);
        unpk2(h.z, v4, v5); unpk2(h.w, v6, v7);
        float4 o0, o1;
        o0.x = fmaxf(fmaf(v0, s0.x, t0.x), 0.f);
        o0.y = fmaxf(fmaf(v1, s0.y, t0.y), 0.f);
        o0.z = fmaxf(fmaf(v2, s0.z, t0.z), 0.f);
        o0.w = fmaxf(fmaf(v3, s0.w, t0.w), 0.f);
        o1.x = fmaxf(fmaf(v4, s1.x, t1.x), 0.f);
        o1.y = fmaxf(fmaf(v5, s1.y, t1.y), 0.f);
        o1.z = fmaxf(fmaf(v6, s1.z, t1.z), 0.f);
        o1.w = fmaxf(fmaf(v7, s1.w, t1.w), 0.f);
        *(float4*)&out[base]     = o0;
        *(float4*)&out[base + 4] = o1;
    }
}

// An[src] += relu(H6*s+t); An[dst] += ...   (atomic, coalesced per row)
__global__ void scatter_e2n(const u16* __restrict__ H6, const float* __restrict__ scsh,
                            const int* __restrict__ src, const int* __restrict__ dst,
                            float* __restrict__ An) {
    size_t stride = (size_t)gridDim.x * blockDim.x;
    for (size_t i = (size_t)blockIdx.x * blockDim.x + threadIdx.x;
         i < (size_t)EDGES * HDIM; i += stride) {
        int e = (int)(i >> 7), h = (int)(i & 127);
        float m = fmaxf(bf2f(H6[i]) * scsh[h] + scsh[128 + h], 0.f);
        atomicAdd(&An[(size_t)src[e] * HDIM + h], m);
        atomicAdd(&An[(size_t)dst[e] * HDIM + h], m);
    }
}

// NI = bf16((1+eps2-degree)*node_rep + An)   (8-wide)
__global__ void node_in_v(const float* __restrict__ node_rep, const float* __restrict__ An,
                          const float* __restrict__ degree, const float* __restrict__ eps2,
                          u16* __restrict__ NI) {
    float e2 = 1.0f + eps2[0];
    size_t stride = (size_t)gridDim.x * blockDim.x;
    for (size_t t = (size_t)blockIdx.x * blockDim.x + threadIdx.x;
         t < (size_t)NODES * 16; t += stride) {
        int n = (int)(t >> 4);
        size_t base = t * 8;
        float c = e2 - degree[n];
        float4 r0 = *(const float4*)&node_rep[base], r1 = *(const float4*)&node_rep[base + 4];
        float4 a0 = *(const float4*)&An[base],       a1 = *(const float4*)&An[base + 4];
        uint4 o;
        o.x = pk_bf16(fmaf(c, r0.x, a0.x), fmaf(c, r0.y, a0.y));
        o.y = pk_bf16(fmaf(c, r0.z, a0.z), fmaf(c, r0.w, a0.w));
        o.z = pk_bf16(fmaf(c, r1.x, a1.x), fmaf(c, r1.y, a1.y));
        o.w = pk_bf16(fmaf(c, r1.z, a1.z), fmaf(c, r1.w, a1.w));
        *(uint4*)&NI[base] = o;
    }
}

// ---------------------------------------------------------------------------
extern "C" void kernel_launch(void* const* d_in, const int* in_sizes, int n_in,
                              void* d_out, int out_size, void* d_ws, size_t ws_size,
                              hipStream_t stream) {
    const float* node_rep = (const float*)d_in[0];
    const float* edge_rep = (const float*)d_in[1];
    const float* degree   = (const float*)d_in[2];
    const int*   src      = (const int*)d_in[3];
    const int*   dst      = (const int*)d_in[4];
    const float* eps1     = (const float*)d_in[5];
    const float* eps2     = (const float*)d_in[6];
    const float* nW1  = (const float*)d_in[7];
    const float* nG1  = (const float*)d_in[8];
    const float* nB1  = (const float*)d_in[9];
    const float* nW2  = (const float*)d_in[10];
    const float* nG2  = (const float*)d_in[11];
    const float* nB2  = (const float*)d_in[12];
    const float* e0W1 = (const float*)d_in[13];
    const float* e0G1 = (const float*)d_in[14];
    const float* e0B1 = (const float*)d_in[15];
    const float* e0W2 = (const float*)d_in[16];
    const float* e0G2 = (const float*)d_in[17];
    const float* e0B2 = (const float*)d_in[18];
    const float* e1W1 = (const float*)d_in[19];
    const float* e1G1 = (const float*)d_in[20];
    const float* e1B1 = (const float*)d_in[21];
    const float* e1W2 = (const float*)d_in[22];
    const float* e1G2 = (const float*)d_in[23];
    const float* e1B2 = (const float*)d_in[24];
    const float* e2W1 = (const float*)d_in[25];
    const float* e2G1 = (const float*)d_in[26];
    const float* e2B1 = (const float*)d_in[27];
    const float* e2W2 = (const float*)d_in[28];
    const float* e2G2 = (const float*)d_in[29];
    const float* e2B2 = (const float*)d_in[30];

    // ---- workspace layout (all 256B aligned) ----
    size_t off = 0;
    auto alloc = [&](size_t bytes) -> void* {
        void* p = (char*)d_ws + off;
        off += (bytes + 255) & ~(size_t)255;
        return p;
    };
    const int NPAD = 50048;                                 // 391*128
    u16*   BUF_A = (u16*)alloc((size_t)EDGES * 256 * 2);    // X0 -> H3
    u16*   BUF_B = (u16*)alloc((size_t)EDGES * 256 * 2);    // H1 -> H5
    u16*   BUF_C = (u16*)alloc((size_t)EDGES * 128 * 2);    // H2 -> H4 -> H6
    u16*   BUF_D = (u16*)alloc((size_t)EDGES * 128 * 2);    // edge_new
    float* S     = (float*)alloc((size_t)NODES * 128 * 4);
    float* An    = (float*)alloc((size_t)NODES * 128 * 4);
    u16*   NI    = (u16*)alloc((size_t)NPAD * 128 * 2);     // padded for gload tail
    u16*   H7    = (u16*)alloc((size_t)NODES * 256 * 2);
    u16*   H8    = (u16*)alloc((size_t)NODES * 128 * 2);
    u16* Wt_e0_1 = (u16*)alloc(256 * 256 * 2);
    u16* Wt_e0_2 = (u16*)alloc(128 * 256 * 2);
    u16* Wt_e1_1 = (u16*)alloc(256 * 128 * 2);
    u16* Wt_e1_2 = (u16*)alloc(128 * 256 * 2);
    u16* Wt_e2_1 = (u16*)alloc(256 * 128 * 2);
    u16* Wt_e2_2 = (u16*)alloc(128 * 256 * 2);
    u16* Wt_n_1  = (u16*)alloc(256 * 128 * 2);
    u16* Wt_n_2  = (u16*)alloc(128 * 256 * 2);
    float* stats = (float*)alloc(8 * 512 * 4);
    float* scsh  = (float*)alloc(8 * 512 * 4);
    if (off > ws_size) return;

    hipMemsetAsync(S,     0, (size_t)NODES * 128 * 4, stream);
    hipMemsetAsync(An,    0, (size_t)NODES * 128 * 4, stream);
    hipMemsetAsync(stats, 0, 8 * 512 * 4, stream);
    hipMemsetAsync(NI + (size_t)NODES * 128, 0,
                   (size_t)(NPAD - NODES) * 128 * 2, stream);   // zero gload pad

    const int EB  = 8192;   // grid-stride blocks, scalar E*128 loops (scatter)
    const int EV  = 4096;   // 8-wide E*16 loops
    const int NV  = 3125;   // 8-wide NODES*16 loops (exact)
    const float invE = 1.0f / (float)EDGES;
    const float invN = 1.0f / (float)NODES;
    const dim3 gE2(3125, 2), gE1(3125, 1), gN2(391, 2), gN1(391, 1);

    // weights -> bf16 transposed
    wt_convert<<<(256 * 256 + 255) / 256, 256, 0, stream>>>(e0W1, Wt_e0_1, 256, 256);
    wt_convert<<<(128 * 256 + 255) / 256, 256, 0, stream>>>(e0W2, Wt_e0_2, 256, 128);
    wt_convert<<<(256 * 128 + 255) / 256, 256, 0, stream>>>(e1W1, Wt_e1_1, 128, 256);
    wt_convert<<<(128 * 256 + 255) / 256, 256, 0, stream>>>(e1W2, Wt_e1_2, 256, 128);
    wt_convert<<<(256 * 128 + 255) / 256, 256, 0, stream>>>(e2W1, Wt_e2_1, 128, 256);
    wt_convert<<<(128 * 256 + 255) / 256, 256, 0, stream>>>(e2W2, Wt_e2_2, 256, 128);
    wt_convert<<<(256 * 128 + 255) / 256, 256, 0, stream>>>(nW1, Wt_n_1, 128, 256);
    wt_convert<<<(128 * 256 + 255) / 256, 256, 0, stream>>>(nW2, Wt_n_2, 256, 128);

    // graph gathers
    scatter_S<<<EB, 256, 0, stream>>>(edge_rep, src, dst, S);
    build_x0_v<<<EV, 256, 0, stream>>>(node_rep, S, src, dst, BUF_A);

    // ---- e0 MLP ----
    gemm_bn<256, false><<<gE2, 256, 0, stream>>>(BUF_A, Wt_e0_1, BUF_B, stats + 0 * 512, EDGES, 256, nullptr);
    bn_finalize<<<1, 256, 0, stream>>>(stats + 0 * 512, e0G1, e0B1, scsh + 0 * 512, 256, invE);
    gemm_bn<256, true><<<gE1, 256, 0, stream>>>(BUF_B, Wt_e0_2, BUF_C, stats + 1 * 512, EDGES, 128, scsh + 0 * 512);
    bn_finalize<<<1, 256, 0, stream>>>(stats + 1 * 512, e0G2, e0B2, scsh + 1 * 512, 128, invE);
    edge_new_v<<<EV, 256, 0, stream>>>(edge_rep, BUF_C, scsh + 1 * 512, eps1, BUF_D);

    // ---- e1 MLP -> edge_out ----
    gemm_bn<128, false><<<gE2, 256, 0, stream>>>(BUF_D, Wt_e1_1, BUF_A, stats + 2 * 512, EDGES, 256, nullptr);
    bn_finalize<<<1, 256, 0, stream>>>(stats + 2 * 512, e1G1, e1B1, scsh + 2 * 512, 256, invE);
    gemm_bn<256, true><<<gE1, 256, 0, stream>>>(BUF_A, Wt_e1_2, BUF_C, stats + 3 * 512, EDGES, 128, scsh + 2 * 512);
    bn_finalize<<<1, 256, 0, stream>>>(stats + 3 * 512, e1G2, e1B2, scsh + 3 * 512, 128, invE);
    affine_out_v<<<EV, 256, 0, stream>>>(BUF_C, scsh + 3 * 512,
                                         (float*)d_out + (size_t)NODES * HDIM,
                                         (size_t)EDGES * 16);

    // ---- e2 MLP -> edge2node scatter ----
    gemm_bn<128, false><<<gE2, 256, 0, stream>>>(BUF_D, Wt_e2_1, BUF_B, stats + 4 * 512, EDGES, 256, nullptr);
    bn_finalize<<<1, 256, 0, stream>>>(stats + 4 * 512, e2G1, e2B1, scsh + 4 * 512, 256, invE);
    gemm_bn<256, true><<<gE1, 256, 0, stream>>>(BUF_B, Wt_e2_2, BUF_C, stats + 5 * 512, EDGES, 128, scsh + 4 * 512);
    bn_finalize<<<1, 256, 0, stream>>>(stats + 5 * 512, e2G2, e2B2, scsh + 5 * 512, 128, invE);
    scatter_e2n<<<EB, 256, 0, stream>>>(BUF_C, scsh + 5 * 512, src, dst, An);

    // ---- node MLP ----
    node_in_v<<<NV, 256, 0, stream>>>(node_rep, An, degree, eps2, NI);
    gemm_bn<128, false><<<gN2, 256, 0, stream>>>(NI, Wt_n_1, H7, stats + 6 * 512, NODES, 256, nullptr);
    bn_finalize<<<1, 256, 0, stream>>>(stats + 6 * 512, nG1, nB1, scsh + 6 * 512, 256, invN);
    gemm_bn<256, true><<<gN1, 256, 0, stream>>>(H7, Wt_n_2, H8, stats + 7 * 512, NODES, 128, scsh + 6 * 512);
    bn_finalize<<<1, 256, 0, stream>>>(stats + 7 * 512, nG2, nB2, scsh + 7 * 512, 128, invN);
    affine_out_v<<<NV, 256, 0, stream>>>(H8, scsh + 7 * 512, (float*)d_out,
                                         (size_t)NODES * 16);
}